// Round 5
// baseline (3698.643 us; speedup 1.0000x reference)
//
#include <hip/hip_runtime.h>
#include <math.h>

// Dims (fixed by the problem)
#define B_  256
#define T_  64
#define D_  6400
#define H_  1000
#define A_  4

#define BM 256
#define BN 128
#define BK 16

// Raw barrier: drain LDS ops only (cross-wave visibility), leave prefetch
// global loads in flight across the barrier (they only feed private VGPRs;
// the compiler inserts its own vmcnt wait before the dependent ds_writes).
#define LGKM_BARRIER()                                         \
  do {                                                         \
    asm volatile("s_waitcnt lgkmcnt(0)" ::: "memory");         \
    __builtin_amdgcn_s_barrier();                              \
  } while (0)

// ---------------------------------------------------------------------------
// Kernel 1: C1[t][b][h] = x[b][t][:] . W1[h][:] + b1[h]
// r4 post-mortem: v_pk_fma_f32 is NOT 2x FLOP rate on gfx950 (157.3 TF spec
// == scalar v_fma rate; counters fit pk=4cyc exactly). So: plain scalar fmaf
// (no marshalling), 512 threads/block with 16x4 micro-tile (acc 64 VGPR) ->
// 4 waves/SIMD from the same 512-block grid (was 2), __launch_bounds__(512,4)
// caps VGPR at 128. Per-element FMA order (k ascending, IEEE fmaf) unchanged
// -> bitwise-identical C1 -> identical spikes.
// ---------------------------------------------------------------------------
__global__ __launch_bounds__(512, 4) void gemm1_kernel(
    const float* __restrict__ x, const float* __restrict__ W1,
    const float* __restrict__ b1, float* __restrict__ C1) {
  __shared__ float As[2][BK][BM + 4];  // [buf][k][m], stride 260
  __shared__ float Bs[2][BK][BN + 4];  // [buf][k][n], stride 132

  const int tid = threadIdx.x;
  const int m0 = blockIdx.y * BM;
  const int n0 = blockIdx.x * BN;
  const int tx = tid & 31;   // n-group: cols tx*4 .. tx*4+3
  const int ty = tid >> 5;   // m-group 0..15: rows {ty*4+j + 64*i}

  const int row_a = tid >> 2;  // 0..127 staging row
  const int col4 = tid & 3;    // float4 column 0..3 (BK=16)

  float acc[16][4];  // [4*i + j][c]
#pragma unroll
  for (int f = 0; f < 16; ++f)
#pragma unroll
    for (int c = 0; c < 4; ++c) acc[f][c] = 0.f;

  float4 av0, av1, bv;

#define LOAD_TILE(kn)                                                         \
  do {                                                                        \
    if ((kn) < D_) {                                                          \
      av0 = *(const float4*)(x + (size_t)(m0 + row_a) * D_ + (kn) +          \
                             col4 * 4);                                       \
      av1 = *(const float4*)(x + (size_t)(m0 + row_a + 128) * D_ + (kn) +    \
                             col4 * 4);                                       \
      const int hh = n0 + row_a;                                              \
      bv = (hh < H_) ? *(const float4*)(W1 + (size_t)hh * D_ + (kn) +        \
                                        col4 * 4)                             \
                     : make_float4(0.f, 0.f, 0.f, 0.f);                       \
    }                                                                         \
  } while (0)

#define STORE_TILE(bufi)                                                      \
  do {                                                                        \
    As[bufi][col4 * 4 + 0][row_a] = av0.x;                                    \
    As[bufi][col4 * 4 + 1][row_a] = av0.y;                                    \
    As[bufi][col4 * 4 + 2][row_a] = av0.z;                                    \
    As[bufi][col4 * 4 + 3][row_a] = av0.w;                                    \
    As[bufi][col4 * 4 + 0][row_a + 128] = av1.x;                              \
    As[bufi][col4 * 4 + 1][row_a + 128] = av1.y;                              \
    As[bufi][col4 * 4 + 2][row_a + 128] = av1.z;                              \
    As[bufi][col4 * 4 + 3][row_a + 128] = av1.w;                              \
    Bs[bufi][col4 * 4 + 0][row_a] = bv.x;                                     \
    Bs[bufi][col4 * 4 + 1][row_a] = bv.y;                                     \
    Bs[bufi][col4 * 4 + 2][row_a] = bv.z;                                     \
    Bs[bufi][col4 * 4 + 3][row_a] = bv.w;                                     \
  } while (0)

  // ---- prologue: tile 0 -> buf0; tile 1 -> regs ----
  LOAD_TILE(0);
  STORE_TILE(0);
  LOAD_TILE(BK);
  LGKM_BARRIER();

  int cur = 0;
  for (int k0 = 0; k0 < D_; k0 += BK) {
    const int nxt = cur ^ 1;
    if (k0 + BK < D_) {
      STORE_TILE(nxt);
      LOAD_TILE(k0 + 2 * BK);
    }
    // ---- compute: 16 k-steps x 64 scalar fmaf ----
#pragma unroll
    for (int k = 0; k < BK; ++k) {
      const float4 a0 = *(const float4*)&As[cur][k][ty * 4];
      const float4 a1 = *(const float4*)&As[cur][k][64 + ty * 4];
      const float4 a2 = *(const float4*)&As[cur][k][128 + ty * 4];
      const float4 a3 = *(const float4*)&As[cur][k][192 + ty * 4];
      const float4 b = *(const float4*)&Bs[cur][k][tx * 4];
      const float am[16] = {a0.x, a0.y, a0.z, a0.w, a1.x, a1.y, a1.z, a1.w,
                            a2.x, a2.y, a2.z, a2.w, a3.x, a3.y, a3.z, a3.w};
      const float bc[4] = {b.x, b.y, b.z, b.w};
#pragma unroll
      for (int f = 0; f < 16; ++f) {
#pragma unroll
        for (int c = 0; c < 4; ++c) {
          acc[f][c] = fmaf(am[f], bc[c], acc[f][c]);
        }
      }
    }
    LGKM_BARRIER();
    cur = nxt;
  }

  // ---- epilogue: +b1, scatter rows to [T][B][H] ----
  const int h0 = n0 + tx * 4;
  float4 bias = (h0 < H_) ? *(const float4*)(b1 + h0)
                          : make_float4(0.f, 0.f, 0.f, 0.f);
#pragma unroll
  for (int f = 0; f < 16; ++f) {
    const int m = m0 + 64 * (f >> 2) + ty * 4 + (f & 3);
    const int bb = m >> 6;  // batch
    const int tt = m & 63;  // timestep
    if (h0 < H_) {
      float4 r;
      r.x = acc[f][0] + bias.x;
      r.y = acc[f][1] + bias.y;
      r.z = acc[f][2] + bias.z;
      r.w = acc[f][3] + bias.w;
      *(float4*)(C1 + (size_t)tt * (B_ * H_) + (size_t)bb * H_ + h0) = r;
    }
  }
#undef LOAD_TILE
#undef STORE_TILE
}

// ---------------------------------------------------------------------------
// Kernel 2: recurrent LIF dynamics. ONE WAVE per batch element, no barriers.
// 256 blocks x 64 threads; 16 h per lane (4x float4 groups, coalesced);
// W2 in 64 registers; shfl-only reduce; layer-2 state lives on lane 0;
// t+1 rows prefetched under the reduce chain.
// ---------------------------------------------------------------------------
__device__ __forceinline__ float sigmoid_f(float z) {
  return 1.0f / (1.0f + expf(-z));
}

__global__ __launch_bounds__(64) void snn_seq_kernel(
    const float* __restrict__ C1, const float* __restrict__ u1,
    const float* __restrict__ W2, const float* __restrict__ b2,
    const float* __restrict__ u2, float* __restrict__ out) {
  const int b = blockIdx.x;
  const int l = threadIdx.x;  // lane 0..63

  // lane handles h = jj*256 + l*4 .. +3, jj = 0..3 (invalid lanes: w=0)
  // W2 in registers, scalar array with constant indices (fully unrolled).
  float wreg[A_][4][4];  // [a][jj][e]
#pragma unroll
  for (int a = 0; a < A_; ++a)
#pragma unroll
    for (int jj = 0; jj < 4; ++jj) {
      const int h = jj * 256 + l * 4;
      float4 w = (h < H_) ? *(const float4*)(W2 + (size_t)a * H_ + h)
                          : make_float4(0.f, 0.f, 0.f, 0.f);
      wreg[a][jj][0] = w.x;
      wreg[a][jj][1] = w.y;
      wreg[a][jj][2] = w.z;
      wreg[a][jj][3] = w.w;
    }
  const float4 b2v = *(const float4*)b2;

  float mem1[4][4], th1[4][4];
#pragma unroll
  for (int jj = 0; jj < 4; ++jj)
#pragma unroll
    for (int e = 0; e < 4; ++e) {
      mem1[jj][e] = 0.f;
      th1[jj][e] = 0.f;
    }
  float mem2[A_] = {0.f, 0.f, 0.f, 0.f};
  float th2[A_] = {0.f, 0.f, 0.f, 0.f};
  float scnt[A_] = {0.f, 0.f, 0.f, 0.f};

  // prefetch t = 0
  float4 c_cur[4], u_cur[4];
#pragma unroll
  for (int jj = 0; jj < 4; ++jj) {
    const int h = jj * 256 + l * 4;
    if (h < H_) {
      const size_t off = (size_t)b * H_ + h;
      c_cur[jj] = *(const float4*)(C1 + off);
      u_cur[jj] = *(const float4*)(u1 + off);
    } else {
      c_cur[jj] = make_float4(0.f, 0.f, 0.f, 0.f);
      u_cur[jj] = make_float4(2.f, 2.f, 2.f, 2.f);  // never spikes
    }
  }
  float4 u2c = *(const float4*)(u2 + (size_t)b * A_);

  for (int t = 0; t < T_; ++t) {
    // ---- issue t+1 loads early: latency hides under LIF + reduce ----
    float4 c_nxt[4], u_nxt[4], u2n;
#pragma unroll
    for (int jj = 0; jj < 4; ++jj) {
      c_nxt[jj] = make_float4(0.f, 0.f, 0.f, 0.f);
      u_nxt[jj] = make_float4(2.f, 2.f, 2.f, 2.f);
    }
    u2n = make_float4(0.f, 0.f, 0.f, 0.f);
    if (t + 1 < T_) {
#pragma unroll
      for (int jj = 0; jj < 4; ++jj) {
        const int h = jj * 256 + l * 4;
        if (h < H_) {
          const size_t off = ((size_t)(t + 1) * B_ + b) * H_ + h;
          c_nxt[jj] = *(const float4*)(C1 + off);
          u_nxt[jj] = *(const float4*)(u1 + off);
        }
      }
      u2n = *(const float4*)(u2 + ((size_t)(t + 1) * B_ + b) * A_);
    }

    // ---- layer-1 LIF + spike-gated W2 accumulation (16 h per lane) ----
    float p0 = 0.f, p1 = 0.f, p2 = 0.f, p3 = 0.f;
#pragma unroll
    for (int jj = 0; jj < 4; ++jj) {
      const float cs[4] = {c_cur[jj].x, c_cur[jj].y, c_cur[jj].z, c_cur[jj].w};
      const float us[4] = {u_cur[jj].x, u_cur[jj].y, u_cur[jj].z, u_cur[jj].w};
#pragma unroll
      for (int e = 0; e < 4; ++e) {
        float m = fmaf(0.9f, mem1[jj][e], cs[e]);
        const float z = m - (1.0f + th1[jj][e]);
        const float p = sigmoid_f(z);
        const float spk = (us[e] < p) ? 1.0f : 0.0f;
        m = (spk != 0.0f) ? 0.0f : m;
        th1[jj][e] = fmaf(0.9f, th1[jj][e], 0.05f * spk);
        mem1[jj][e] = m;
        p0 = fmaf(spk, wreg[0][jj][e], p0);
        p1 = fmaf(spk, wreg[1][jj][e], p1);
        p2 = fmaf(spk, wreg[2][jj][e], p2);
        p3 = fmaf(spk, wreg[3][jj][e], p3);
      }
    }

    // ---- wave-level tree reduce (64 lanes, no LDS, no barrier) ----
#pragma unroll
    for (int off = 32; off >= 1; off >>= 1) {
      p0 += __shfl_down(p0, off);
      p1 += __shfl_down(p1, off);
      p2 += __shfl_down(p2, off);
      p3 += __shfl_down(p3, off);
    }

    // ---- layer-2 LIF on lane 0 (state never leaves lane 0) ----
    if (l == 0) {
      const float cur2[4] = {p0 + b2v.x, p1 + b2v.y, p2 + b2v.z, p3 + b2v.w};
      const float uu[4] = {u2c.x, u2c.y, u2c.z, u2c.w};
#pragma unroll
      for (int a = 0; a < A_; ++a) {
        float m = fmaf(0.9f, mem2[a], cur2[a]);
        const float z = m - (1.0f + th2[a]);
        const float p = sigmoid_f(z);
        const float spk = (uu[a] < p) ? 1.0f : 0.0f;
        mem2[a] = (spk != 0.0f) ? 0.0f : m;
        th2[a] = fmaf(0.9f, th2[a], 0.05f * spk);
        scnt[a] += spk;
      }
    }

#pragma unroll
    for (int jj = 0; jj < 4; ++jj) {
      c_cur[jj] = c_nxt[jj];
      u_cur[jj] = u_nxt[jj];
    }
    u2c = u2n;
  }

  if (l == 0) {
    float4 r;
    r.x = scnt[0] * (1.0f / 64.0f);
    r.y = scnt[1] * (1.0f / 64.0f);
    r.z = scnt[2] * (1.0f / 64.0f);
    r.w = scnt[3] * (1.0f / 64.0f);
    *(float4*)(out + (size_t)b * A_) = r;
  }
}

extern "C" void kernel_launch(void* const* d_in, const int* in_sizes, int n_in,
                              void* d_out, int out_size, void* d_ws,
                              size_t ws_size, hipStream_t stream) {
  const float* x = (const float*)d_in[0];   // [B,T,D]
  const float* W1 = (const float*)d_in[1];  // [H,D]
  const float* b1 = (const float*)d_in[2];  // [H]
  const float* W2 = (const float*)d_in[3];  // [A,H]
  const float* b2 = (const float*)d_in[4];  // [A]
  const float* u1 = (const float*)d_in[5];  // [T,B,H]
  const float* u2 = (const float*)d_in[6];  // [T,B,A]
  float* out = (float*)d_out;               // [B,A]
  float* C1 = (float*)d_ws;                 // [T,B,H] = 65.536 MB scratch

  dim3 g1((H_ + BN - 1) / BN, (B_ * T_) / BM);  // (8, 64)
  gemm1_kernel<<<g1, 512, 0, stream>>>(x, W1, b1, C1);
  snn_seq_kernel<<<B_, 64, 0, stream>>>(C1, u1, W2, b2, u2, out);
}